// Round 8
// baseline (451.471 us; speedup 1.0000x reference)
//
#include <hip/hip_runtime.h>

typedef unsigned short ushort_t;
typedef unsigned int   uint_t;
typedef __attribute__((ext_vector_type(8))) short  short8;
typedef __attribute__((ext_vector_type(4))) float  floatx4;

#define NROWS 131072
#define BM    64      // rows per block (one tower per block)
#define SX    328     // x-hat bf16 LDS row stride (ushorts); cols >=292 zeroed to 320
#define SH    264     // h bf16 LDS row stride (ushorts)

// d_ws bf16 region (ushort element offsets) — chunk-major: [kc][col(256)][k(32)]
#define W1_OFF 0        // 10 chunks
#define P1_OFF 81920    // 10 chunks
#define W2_OFF 163840   // 8 chunks
#define P2_OFF 229376   // 8 chunks
#define P3BF_OFF 294912 // 8 chunks x [16 cols][32] bf16 frag layout (cols>=10 zero)
#define BF16_BYTES 598016
// d_ws float region (float element offsets, base = ws + BF16_BYTES)
#define B1_OFF  0
#define PB1_OFF 256
#define B2_OFF  512
#define PB2_OFF 768
#define W3_OFF  1024
#define B3_OFF  3840
#define PB3_OFF 3841

__device__ __forceinline__ float b2f(ushort_t u){
    union { uint_t i; float f; } v; v.i = ((uint_t)u) << 16; return v.f;
}
__device__ __forceinline__ ushort_t f2b(float f){
    union { uint_t i; float f; } v; v.f = f;
    uint_t b = v.i;
    b += 0x7FFFu + ((b >> 16) & 1u);   // RNE
    return (ushort_t)(b >> 16);
}

// ---------------- prologue: fold LN gain/bias into linears, fp32 -> bf16 ----
__global__ __launch_bounds__(256) void bcq_prep(
    const float* __restrict__ ln1w, const float* __restrict__ ln1b,
    const float* __restrict__ ln2w, const float* __restrict__ ln2b,
    const float* __restrict__ ln3w, const float* __restrict__ ln3b,
    const float* __restrict__ n1g,  const float* __restrict__ n1b,
    const float* __restrict__ n2g,  const float* __restrict__ n2b,
    const float* __restrict__ n3g,  const float* __restrict__ n3b,
    const float* __restrict__ p1w,  const float* __restrict__ p1b,
    const float* __restrict__ p2w,  const float* __restrict__ p2b,
    const float* __restrict__ p3w,  const float* __restrict__ p3b,
    const float* __restrict__ pn1g, const float* __restrict__ pn1b,
    const float* __restrict__ pn2g, const float* __restrict__ pn2b,
    const float* __restrict__ pn3g, const float* __restrict__ pn3b,
    ushort_t* __restrict__ wbf, float* __restrict__ wf)
{
    const int bid = blockIdx.x, tid = threadIdx.x;
    if (bid < 128){
        // layer 1 (K=292 padded to 320): W1 then P1
        for (int i = bid*256 + tid; i < 163840; i += 128*256){
            const int which = i / 81920;            // 0=W1, 1=P1
            const int r  = i - which*81920;
            const int kc = r >> 13;                  // /8192
            const int t  = r & 8191;
            const int c  = t >> 5, kk = t & 31;
            const int k  = kc*32 + kk;
            const float* src = which ? p1w  : ln1w;
            const float* g   = which ? pn1g : n1g;
            ushort_t v = 0;
            if (k < 292) v = f2b(src[c*292 + k] * g[k]);
            wbf[i] = v;
        }
        // layer 2 (K=256): W2 then P2
        for (int i = bid*256 + tid; i < 131072; i += 128*256){
            const int which = i >> 16;
            const int r  = i & 65535;
            const int kc = r >> 13;
            const int t  = r & 8191;
            const int c  = t >> 5, kk = t & 31;
            const int k  = kc*32 + kk;
            const float* src = which ? p2w  : ln2w;
            const float* g   = which ? pn2g : n2g;
            wbf[W2_OFF + i] = f2b(src[c*256 + k] * g[k]);
        }
    } else if (bid < 384){
        const int d = (bid - 128)*4 + (tid >> 6);
        const int lane = tid & 63;
        const float *w, *nb, *bs; int K, outoff; const int c = d & 255;
        if (d < 256)      { w = ln1w; nb = n1b;  bs = ln1b; K = 292; outoff = B1_OFF; }
        else if (d < 512) { w = p1w;  nb = pn1b; bs = p1b;  K = 292; outoff = PB1_OFF; }
        else if (d < 768) { w = ln2w; nb = n2b;  bs = ln2b; K = 256; outoff = B2_OFF; }
        else              { w = p2w;  nb = pn2b; bs = p2b;  K = 256; outoff = PB2_OFF; }
        float s = 0.f;
        for (int k = lane; k < K; k += 64) s += w[c*K + k] * nb[k];
        for (int off = 32; off; off >>= 1) s += __shfl_down(s, off);
        if (lane == 0) wf[outoff + c] = s + bs[c];
    } else if (bid == 384){
        wf[W3_OFF + tid] = ln3w[tid] * n3g[tid];
        // P3 in bf16 MFMA B-frag layout: [kc][col(16)][kk(32)], cols >=10 zero
        for (int i = tid; i < 4096; i += 256){
            const int kc = i >> 9, t = i & 511, c = t >> 5, kk = t & 31;
            const int k = kc*32 + kk;
            ushort_t vv = 0;
            if (c < 10) vv = f2b(p3w[c*256 + k] * pn3g[k]);
            wbf[P3BF_OFF + i] = vv;
        }
    } else {
        const int g32 = tid >> 5, l32 = tid & 31;
        const int d = (bid - 385)*8 + g32;                   // valid < 11
        if (d < 11){
            const float* w  = (d == 0) ? ln3w : (p3w + (d-1)*256);
            const float* nb = (d == 0) ? n3b  : pn3b;
            float s = 0.f;
            for (int k = l32; k < 256; k += 32) s += w[k] * nb[k];
            for (int off = 16; off; off >>= 1) s += __shfl_xor(s, off);
            if (l32 == 0){
                if (d == 0) wf[B3_OFF] = s + ln3b[0];
                else        wf[PB3_OFF + d - 1] = s + p3b[d - 1];
            }
        }
    }
}

// ---------------- main ------------------------------------------------------
// 1024 threads = 16 waves. Wave w = (r2 = w>>3, c8 = w&7) owns the 32x32 patch
// rows [r2*32,+32) x cols [c8*32,+32). Per kc: 2 A-frags (LDS), 2 B-frags (L2,
// depth-2 reg prefetch), 4 MFMAs. acc[2][2] = 16 AGPR; K-loop arch ~44 VGPR ->
// peak unified ~60 <= 64 => 8-waves/SIMD register tier => 2 blocks/CU by LDS
// => 32 waves/CU (vs 16 in the 512-thread/96-reg shape).
// Fused LN epilogue identical in math to the proven R6 version.
// Safe for sOut aliasing sIn: all sIn reads complete before internal barrier 1.
template<int FULLKC>
__device__ __forceinline__ void gemm1024ln(
    const ushort_t* sIn, const int astride, const ushort_t* __restrict__ Wg,
    const float* __restrict__ biasf, ushort_t* sOut,
    float* sRed, float* sM, float* sR, int tid)
{
    const int lane = tid & 63, wave = tid >> 6;        // 16 waves
    const int l15 = lane & 15, quad = lane >> 4;
    const int rowbase = (wave >> 3) * 32;
    const int c8 = wave & 7;
    const int colbase = c8 * 32;
    const ushort_t* arow = sIn + (rowbase + l15)*astride + quad*8; // + rt*16*astride + kc*32
    // chunk-major: frag addr = (colbase + nt*16 + l15)*32 + quad*8 + kc*8192
    const ushort_t* wl = Wg + (colbase + l15)*32 + quad*8;

    floatx4 acc[2][2];                                 // [nt][rt] = 16 AGPR
#pragma unroll
    for (int nt = 0; nt < 2; ++nt)
#pragma unroll
        for (int rt = 0; rt < 2; ++rt) acc[nt][rt] = (floatx4){0,0,0,0};

    short8 bb0[2], bb1[2];                             // depth-2 B prefetch (16 VGPR)
#pragma unroll
    for (int nt = 0; nt < 2; ++nt) bb0[nt] = *(const short8*)(wl + nt*512);
#pragma unroll
    for (int nt = 0; nt < 2; ++nt) bb1[nt] = *(const short8*)(wl + nt*512 + 8192);

#pragma unroll
    for (int kc = 0; kc < FULLKC; ++kc){
        short8 bnew[2];
        if (kc + 2 < FULLKC){
#pragma unroll
            for (int nt = 0; nt < 2; ++nt)
                bnew[nt] = *(const short8*)(wl + nt*512 + (kc + 2)*8192);
        }
        short8 a[2];
#pragma unroll
        for (int rt = 0; rt < 2; ++rt)
            a[rt] = *(const short8*)(arow + rt*16*astride + kc*32);
#pragma unroll
        for (int nt = 0; nt < 2; ++nt){
            const short8 bc = (kc & 1) ? bb1[nt] : bb0[nt];
#pragma unroll
            for (int rt = 0; rt < 2; ++rt)
                acc[nt][rt] = __builtin_amdgcn_mfma_f32_16x16x32_bf16(a[rt], bc, acc[nt][rt], 0, 0, 0);
        }
        if (kc + 2 < FULLKC){
#pragma unroll
            for (int nt = 0; nt < 2; ++nt){
                if (kc & 1) bb1[nt] = bnew[nt]; else bb0[nt] = bnew[nt];
            }
        }
    }

    // ---- fused LN epilogue ----
    float bia[2];
#pragma unroll
    for (int nt = 0; nt < 2; ++nt) bia[nt] = biasf[colbase + nt*16 + l15];

    // y = relu(acc+bias) stored back into acc; per-(rt,i) row partials over 2 col-tiles
    float ps[2][4], pq[2][4];
#pragma unroll
    for (int rt = 0; rt < 2; ++rt)
#pragma unroll
        for (int i = 0; i < 4; ++i){
            float s = 0.f, q = 0.f;
#pragma unroll
            for (int nt = 0; nt < 2; ++nt){
                float y = fmaxf(acc[nt][rt][i] + bia[nt], 0.f);
                acc[nt][rt][i] = y;
                s += y; q += y*y;
            }
            ps[rt][i] = s; pq[rt][i] = q;
        }
    // reduce across the 16 lanes (cols) of the quad group
#pragma unroll
    for (int off = 1; off <= 8; off <<= 1){
#pragma unroll
        for (int rt = 0; rt < 2; ++rt)
#pragma unroll
            for (int i = 0; i < 4; ++i){
                ps[rt][i] += __shfl_xor(ps[rt][i], off);
                pq[rt][i] += __shfl_xor(pq[rt][i], off);
            }
    }
    if (l15 == 0){
#pragma unroll
        for (int rt = 0; rt < 2; ++rt)
#pragma unroll
            for (int i = 0; i < 4; ++i){
                const int row = rowbase + rt*16 + quad*4 + i;
                sRed[row*16 + c8*2 + 0] = ps[rt][i];
                sRed[row*16 + c8*2 + 1] = pq[rt][i];
            }
    }
    __syncthreads();                                   // also drains all sIn reads
    if (tid < 64){
        float ss = 0.f, qq = 0.f;
#pragma unroll
        for (int w = 0; w < 8; ++w){ ss += sRed[tid*16 + w*2]; qq += sRed[tid*16 + w*2 + 1]; }
        float m = ss * (1.f/256.f);
        float var = fmaxf(qq * (1.f/256.f) - m*m, 0.f);
        sM[tid] = m; sR[tid] = rsqrtf(var + 1e-5f);
    }
    __syncthreads();
    // normalize from registers, write bf16 (sOut may alias sIn — reads done)
#pragma unroll
    for (int rt = 0; rt < 2; ++rt)
#pragma unroll
        for (int i = 0; i < 4; ++i){
            const int row = rowbase + rt*16 + quad*4 + i;
            const float m = sM[row], r = sR[row];
#pragma unroll
            for (int nt = 0; nt < 2; ++nt)
                sOut[row*SH + colbase + nt*16 + l15] = f2b((acc[nt][rt][i] - m) * r);
        }
}

__global__ __launch_bounds__(1024)
__attribute__((amdgpu_waves_per_eu(8, 8)))   // 64-unified budget: K-loop peak ~60 -> 8 waves/SIMD tier
void bcq_main(
    const float* __restrict__ cum, const float* __restrict__ inp, const float* __restrict__ pos,
    const ushort_t* __restrict__ wbf, const float* __restrict__ wf, float* __restrict__ out)
{
    // 46592 B LDS -> 2 blocks/CU = 32 waves/CU at the 64-reg tier
    __shared__ __align__(16) char sMem[46592];
    ushort_t* sX     = (ushort_t*)sMem;            // 41984 B: x-hat (stride SX, 64 rows)
    ushort_t* sH     = (ushort_t*)sMem;            // alias:   h     (stride SH, 33792 B)
    float*    sRed   = (float*)(sMem + 41984);     // 4096 B scratch (score buf aliases)
    float*    sScore = sRed;                       // 2560 B used at the end
    float*    sM     = (float*)(sMem + 46080);     // 256 B
    float*    sR     = (float*)(sMem + 46336);     // 256 B

    const int tid = threadIdx.x;
    const int r16 = tid >> 4, p16 = tid & 15;      // 16 threads per row, 64 rows
    const int tower = blockIdx.x & 1;              // pair adjacent blocks on one row-tile
    const size_t rowg = (size_t)(blockIdx.x >> 1) * BM;

    const float* cr = cum + (rowg + r16)*146;
    const float* ir = inp + (rowg + r16)*136;
    const float* pr = pos + (rowg + r16)*10;

    // ---- phase 0, pass 1: LN1 stats ONLY — x not kept live across barriers
    {
        float s = 0.f, sq = 0.f;
#pragma unroll
        for (int i = 0; i < 19; ++i){
            const int c = p16 + (i << 4);
            if (c < 292){
                float x = (c < 146) ? cr[c] : (c < 282) ? ir[c-146] : pr[c-282];
                s += x; sq += x*x;
            }
        }
        // 16-lane row reduce in-register
#pragma unroll
        for (int off = 1; off <= 8; off <<= 1){ s += __shfl_xor(s, off); sq += __shfl_xor(sq, off); }
        if (p16 == 0){
            float m = s * (1.f/292.f);
            float var = fmaxf(sq * (1.f/292.f) - m*m, 0.f);
            sM[r16] = m; sR[r16] = rsqrtf(var + 1e-5f);
        }
        // zero sX cols [292,320) (A reads stop at 320)
#pragma unroll
        for (int j = 0; j < 2; ++j){
            const int c = 292 + p16 + (j << 4);
            if (c < 320) sX[r16*SX + c] = 0;
        }
    }
    __syncthreads();
    asm volatile("" ::: "memory");   // force x re-load (L2-hot) — no big live range
    // ---- phase 0, pass 2: reload x, normalize, store bf16 x-hat ----
    {
        const float mr = sM[r16], rs = sR[r16];
#pragma unroll
        for (int i = 0; i < 19; ++i){
            const int c = p16 + (i << 4);
            if (c < 292){
                float x = (c < 146) ? cr[c] : (c < 282) ? ir[c-146] : pr[c-282];
                sX[r16*SX + c] = f2b((x - mr) * rs);
            }
        }
    }
    __syncthreads();

    if (tower == 0){
        // ================= value tower =================
        gemm1024ln<10>(sX, SX, wbf + W1_OFF, wf + B1_OFF, sH, sRed, sM, sR, tid);
        __syncthreads();
        gemm1024ln<8>(sH, SH, wbf + W2_OFF, wf + B2_OFF, sH, sRed, sM, sR, tid);
        __syncthreads();
        // value head: dot(x-hat3, w3') + B3, 16 threads/row
        const ushort_t* ap = sH + r16*SH + p16*16;
        const float* w3 = wf + W3_OFF + p16*16;
        float s = 0.f;
#pragma unroll
        for (int c = 0; c < 16; ++c) s += b2f(ap[c]) * w3[c];
#pragma unroll
        for (int off = 1; off <= 8; off <<= 1) s += __shfl_xor(s, off);
        if (p16 == 0) out[rowg + r16] = s + wf[B3_OFF];
    } else {
        // ================= probability tower =================
        gemm1024ln<10>(sX, SX, wbf + P1_OFF, wf + PB1_OFF, sH, sRed, sM, sR, tid);
        __syncthreads();
        gemm1024ln<8>(sH, SH, wbf + P2_OFF, wf + PB2_OFF, sH, sRed, sM, sR, tid);
        __syncthreads();
        // score head (256->10) via MFMA on waves 0,1 (32 rows each)
        const int lane = tid & 63, wave = tid >> 6;
        const int l15 = lane & 15, quad = lane >> 4;
        if (wave < 2){
            const int rb = wave*32;
            const ushort_t* ar0 = sH + (rb + l15)*SH + quad*8;
            const ushort_t* ar1 = ar0 + 16*SH;
            const ushort_t* wl = wbf + P3BF_OFF + l15*32 + quad*8;
            floatx4 c0 = (floatx4){0,0,0,0}, c1 = (floatx4){0,0,0,0};
#pragma unroll
            for (int kc = 0; kc < 8; ++kc){
                short8 b  = *(const short8*)(wl + kc*512);
                short8 a0 = *(const short8*)(ar0 + kc*32);
                short8 a1 = *(const short8*)(ar1 + kc*32);
                c0 = __builtin_amdgcn_mfma_f32_16x16x32_bf16(a0, b, c0, 0, 0, 0);
                c1 = __builtin_amdgcn_mfma_f32_16x16x32_bf16(a1, b, c1, 0, 0, 0);
            }
            if (l15 < 10){
                const float bia = wf[PB3_OFF + l15];
#pragma unroll
                for (int i = 0; i < 4; ++i){
                    sScore[(rb + quad*4 + i)*10 + l15]      = c0[i] + bia;
                    sScore[(rb + 16 + quad*4 + i)*10 + l15] = c1[i] + bia;
                }
            }
        }
        __syncthreads();
        if (tid < 64){
            float m = -1e30f;
#pragma unroll
            for (int j = 0; j < 10; ++j) m = fmaxf(m, sScore[tid*10 + j]);
            float l = 0.f;
#pragma unroll
            for (int j = 0; j < 10; ++j) l += expf(sScore[tid*10 + j] - m);
            l = logf(l);
            const size_t rg = rowg + tid;
#pragma unroll
            for (int j = 0; j < 10; ++j){
                const float sv = sScore[tid*10 + j];
                out[(size_t)NROWS    + rg*10 + j] = sv - m - l;
                out[(size_t)NROWS*11 + rg*10 + j] = sv;
            }
        }
    }
}

extern "C" void kernel_launch(void* const* d_in, const int* in_sizes, int n_in,
                              void* d_out, int out_size, void* d_ws, size_t ws_size,
                              hipStream_t stream) {
    (void)in_sizes; (void)n_in; (void)ws_size; (void)out_size;
    const float* cum  = (const float*)d_in[0];
    const float* inp  = (const float*)d_in[1];
    const float* pos  = (const float*)d_in[2];
    const float* ln1w = (const float*)d_in[3];
    const float* ln1b = (const float*)d_in[4];
    const float* ln2w = (const float*)d_in[5];
    const float* ln2b = (const float*)d_in[6];
    const float* ln3w = (const float*)d_in[7];
    const float* ln3b = (const float*)d_in[8];
    const float* n1g  = (const float*)d_in[9];
    const float* n1b  = (const float*)d_in[10];
    const float* n2g  = (const float*)d_in[11];
    const float* n2b  = (const float*)d_in[12];
    const float* n3g  = (const float*)d_in[13];
    const float* n3b  = (const float*)d_in[14];
    const float* p1w  = (const float*)d_in[15];
    const float* p1b  = (const float*)d_in[16];
    const float* p2w  = (const float*)d_in[17];
    const float* p2b  = (const float*)d_in[18];
    const float* p3w  = (const float*)d_in[19];
    const float* p3b  = (const float*)d_in[20];
    const float* pn1g = (const float*)d_in[21];
    const float* pn1b = (const float*)d_in[22];
    const float* pn2g = (const float*)d_in[23];
    const float* pn2b = (const float*)d_in[24];
    const float* pn3g = (const float*)d_in[25];
    const float* pn3b = (const float*)d_in[26];

    ushort_t* wbf = (ushort_t*)d_ws;
    float*    wf  = (float*)((char*)d_ws + BF16_BYTES);
    float*    out = (float*)d_out;

    hipLaunchKernelGGL(bcq_prep, dim3(387), dim3(256), 0, stream,
        ln1w, ln1b, ln2w, ln2b, ln3w, ln3b,
        n1g, n1b, n2g, n2b, n3g, n3b,
        p1w, p1b, p2w, p2b, p3w, p3b,
        pn1g, pn1b, pn2g, pn2b, pn3g, pn3b,
        wbf, wf);

    hipLaunchKernelGGL(bcq_main, dim3((NROWS/BM)*2), dim3(1024), 0, stream,
        cum, inp, pos, wbf, wf, out);
}

// Round 9
// 450.097 us; speedup vs baseline: 1.0031x; 1.0031x over previous
//
#include <hip/hip_runtime.h>

typedef unsigned short ushort_t;
typedef unsigned int   uint_t;
typedef __attribute__((ext_vector_type(8))) short  short8;
typedef __attribute__((ext_vector_type(4))) float  floatx4;

#define NROWS 131072
#define BM    64      // rows per block (one tower per block)
#define SX    328     // raw x bf16 LDS row stride (ushorts); cols >=292 zeroed to 320
#define SH    264     // h bf16 LDS row stride (ushorts)

// d_ws bf16 region (ushort element offsets) — chunk-major: [kc][col(256)][k(32)]
#define W1_OFF 0        // 10 chunks
#define P1_OFF 81920    // 10 chunks
#define W2_OFF 163840   // 8 chunks
#define P2_OFF 229376   // 8 chunks
#define P3BF_OFF 294912 // 8 chunks x [16 cols][32] bf16 frag layout (cols>=10 zero)
#define BF16_BYTES 598016
// d_ws float region (float element offsets, base = ws + BF16_BYTES)
#define B1_OFF   0
#define PB1_OFF  256
#define B2_OFF   512
#define PB2_OFF  768
#define W3_OFF   1024
#define B3_OFF   3840
#define PB3_OFF  3841   // ..3850
#define CS1_OFF  4096
#define CSP1_OFF 4352
#define CS2_OFF  4608
#define CSP2_OFF 4864
#define CS3_OFF  5120
#define CSP3_OFF 5121   // ..5130

__device__ __forceinline__ float b2f(ushort_t u){
    union { uint_t i; float f; } v; v.i = ((uint_t)u) << 16; return v.f;
}
__device__ __forceinline__ ushort_t f2b(float f){
    union { uint_t i; float f; } v; v.f = f;
    uint_t b = v.i;
    b += 0x7FFFu + ((b >> 16) & 1u);   // RNE
    return (ushort_t)(b >> 16);
}

// ---------------- prologue: fold LN gain/bias into linears, fp32 -> bf16 ----
__global__ __launch_bounds__(256) void bcq_prep(
    const float* __restrict__ ln1w, const float* __restrict__ ln1b,
    const float* __restrict__ ln2w, const float* __restrict__ ln2b,
    const float* __restrict__ ln3w, const float* __restrict__ ln3b,
    const float* __restrict__ n1g,  const float* __restrict__ n1b,
    const float* __restrict__ n2g,  const float* __restrict__ n2b,
    const float* __restrict__ n3g,  const float* __restrict__ n3b,
    const float* __restrict__ p1w,  const float* __restrict__ p1b,
    const float* __restrict__ p2w,  const float* __restrict__ p2b,
    const float* __restrict__ p3w,  const float* __restrict__ p3b,
    const float* __restrict__ pn1g, const float* __restrict__ pn1b,
    const float* __restrict__ pn2g, const float* __restrict__ pn2b,
    const float* __restrict__ pn3g, const float* __restrict__ pn3b,
    ushort_t* __restrict__ wbf, float* __restrict__ wf)
{
    const int bid = blockIdx.x, tid = threadIdx.x;
    if (bid < 128){
        // layer 1 (K=292 padded to 320): W1 then P1
        for (int i = bid*256 + tid; i < 163840; i += 128*256){
            const int which = i / 81920;            // 0=W1, 1=P1
            const int r  = i - which*81920;
            const int kc = r >> 13;                  // /8192
            const int t  = r & 8191;
            const int c  = t >> 5, kk = t & 31;
            const int k  = kc*32 + kk;
            const float* src = which ? p1w  : ln1w;
            const float* g   = which ? pn1g : n1g;
            ushort_t v = 0;
            if (k < 292) v = f2b(src[c*292 + k] * g[k]);
            wbf[i] = v;
        }
        // layer 2 (K=256): W2 then P2
        for (int i = bid*256 + tid; i < 131072; i += 128*256){
            const int which = i >> 16;
            const int r  = i & 65535;
            const int kc = r >> 13;
            const int t  = r & 8191;
            const int c  = t >> 5, kk = t & 31;
            const int k  = kc*32 + kk;
            const float* src = which ? p2w  : ln2w;
            const float* g   = which ? pn2g : n2g;
            wbf[W2_OFF + i] = f2b(src[c*256 + k] * g[k]);
        }
    } else if (bid < 384){
        const int d = (bid - 128)*4 + (tid >> 6);
        const int lane = tid & 63;
        const float *w, *nb, *bs; int K, outoff; const int c = d & 255;
        if (d < 256)      { w = ln1w; nb = n1b;  bs = ln1b; K = 292; outoff = B1_OFF; }
        else if (d < 512) { w = p1w;  nb = pn1b; bs = p1b;  K = 292; outoff = PB1_OFF; }
        else if (d < 768) { w = ln2w; nb = n2b;  bs = ln2b; K = 256; outoff = B2_OFF; }
        else              { w = p2w;  nb = pn2b; bs = p2b;  K = 256; outoff = PB2_OFF; }
        float s = 0.f;
        for (int k = lane; k < K; k += 64) s += w[c*K + k] * nb[k];
        for (int off = 32; off; off >>= 1) s += __shfl_down(s, off);
        if (lane == 0) wf[outoff + c] = s + bs[c];
    } else if (bid == 384){
        wf[W3_OFF + tid] = ln3w[tid] * n3g[tid];
        // P3 in bf16 MFMA B-frag layout: [kc][col(16)][kk(32)], cols >=10 zero
        for (int i = tid; i < 4096; i += 256){
            const int kc = i >> 9, t = i & 511, c = t >> 5, kk = t & 31;
            const int k = kc*32 + kk;
            ushort_t vv = 0;
            if (c < 10) vv = f2b(p3w[c*256 + k] * pn3g[k]);
            wbf[P3BF_OFF + i] = vv;
        }
    } else if (bid < 387){
        const int g32 = tid >> 5, l32 = tid & 31;
        const int d = (bid - 385)*8 + g32;                   // valid < 11
        if (d < 11){
            const float* w  = (d == 0) ? ln3w : (p3w + (d-1)*256);
            const float* nb = (d == 0) ? n3b  : pn3b;
            float s = 0.f;
            for (int k = l32; k < 256; k += 32) s += w[k] * nb[k];
            for (int off = 16; off; off >>= 1) s += __shfl_xor(s, off);
            if (l32 == 0){
                if (d == 0) wf[B3_OFF] = s + ln3b[0];
                else        wf[PB3_OFF + d - 1] = s + p3b[d - 1];
            }
        }
    } else if (bid < 643){
        // csum[c] = sum_k W'[c,k] (gain-folded row sums) for the LN fold
        const int d = (bid - 387)*4 + (tid >> 6);
        const int lane = tid & 63;
        const float *w, *g; int K, outoff; const int c = d & 255;
        if (d < 256)      { w = ln1w; g = n1g;  K = 292; outoff = CS1_OFF; }
        else if (d < 512) { w = p1w;  g = pn1g; K = 292; outoff = CSP1_OFF; }
        else if (d < 768) { w = ln2w; g = n2g;  K = 256; outoff = CS2_OFF; }
        else              { w = p2w;  g = pn2g; K = 256; outoff = CSP2_OFF; }
        float s = 0.f;
        for (int k = lane; k < K; k += 64) s += w[c*K + k] * g[k];
        for (int off = 32; off; off >>= 1) s += __shfl_down(s, off);
        if (lane == 0) wf[outoff + c] = s;
    } else {
        // head csums: CS3 = sum(ln3w*n3g); CSP3[j] = sum_k p3w[j,k]*pn3g[k]
        const int g32 = tid >> 5, l32 = tid & 31;
        const int d = (bid - 643)*8 + g32;                   // valid < 11
        if (d < 11){
            const float* w = (d == 0) ? ln3w : (p3w + (d-1)*256);
            const float* g = (d == 0) ? n3g  : pn3g;
            float s = 0.f;
            for (int k = l32; k < 256; k += 32) s += w[k] * g[k];
            for (int off = 16; off; off >>= 1) s += __shfl_xor(s, off);
            if (l32 == 0){
                if (d == 0) wf[CS3_OFF] = s;
                else        wf[CSP3_OFF + d - 1] = s;
            }
        }
    }
}

// ---------------- main ------------------------------------------------------
// GEMM on RAW (un-normalized) bf16 input; input-LN folded into the epilogue:
//   y = relu( r_row*acc + (B[c] - (m*r)_row*csum[c]) )
// Raw y written back (bf16); its LN stats reduced for the NEXT layer.
// 8 waves: wave w owns cols [w*32,w*32+32) over all 64 rows; depth-2 B prefetch
// (the exact R6 K-loop — proven VGPR=64, no spill). 2 barriers per layer.
// sOut may alias sIn: raw write happens after the barrier that drains all reads.
template<int FULLKC>
__device__ __forceinline__ void gemm64raw(
    const ushort_t* sIn, int astride, const ushort_t* __restrict__ Wg,
    const float* __restrict__ biasf, const float* __restrict__ csumf,
    ushort_t* sOut, float* sRed, float* sM, float* sR, int tid)
{
    const int lane = tid & 63, wave = tid >> 6;        // 8 waves
    const int l15 = lane & 15, quad = lane >> 4;
    const int colbase = wave * 32;
    const ushort_t* arow = sIn + l15*astride + quad*8; // + rt*16*astride + kc*32
    // chunk-major: frag addr = (colbase + nt*16 + l15)*32 + quad*8 + kc*8192
    const ushort_t* wl = Wg + (colbase + l15)*32 + quad*8;

    floatx4 acc[2][4];                                 // [nt][rt] = 32 AGPRs
#pragma unroll
    for (int nt = 0; nt < 2; ++nt)
#pragma unroll
        for (int rt = 0; rt < 4; ++rt) acc[nt][rt] = (floatx4){0,0,0,0};

    short8 bb0[2], bb1[2];                             // depth-2 prefetch (R6-proven)
#pragma unroll
    for (int nt = 0; nt < 2; ++nt) bb0[nt] = *(const short8*)(wl + nt*512);
#pragma unroll
    for (int nt = 0; nt < 2; ++nt) bb1[nt] = *(const short8*)(wl + nt*512 + 8192);

#pragma unroll
    for (int kc = 0; kc < FULLKC; ++kc){
        short8 bnew[2];
        if (kc + 2 < FULLKC){
#pragma unroll
            for (int nt = 0; nt < 2; ++nt)
                bnew[nt] = *(const short8*)(wl + nt*512 + (kc + 2)*8192);
        }
        short8 a[4];
#pragma unroll
        for (int rt = 0; rt < 4; ++rt)
            a[rt] = *(const short8*)(arow + rt*16*astride + kc*32);
#pragma unroll
        for (int nt = 0; nt < 2; ++nt){
            const short8 bc = (kc & 1) ? bb1[nt] : bb0[nt];
#pragma unroll
            for (int rt = 0; rt < 4; ++rt)
                acc[nt][rt] = __builtin_amdgcn_mfma_f32_16x16x32_bf16(a[rt], bc, acc[nt][rt], 0, 0, 0);
        }
        if (kc + 2 < FULLKC){
#pragma unroll
            for (int nt = 0; nt < 2; ++nt){
                if (kc & 1) bb1[nt] = bnew[nt]; else bb0[nt] = bnew[nt];
            }
        }
    }

    // ---- epilogue: fold input-LN, relu, stats of raw output ----
    float b_[2], cs_[2];
#pragma unroll
    for (int nt = 0; nt < 2; ++nt){
        const int c = colbase + nt*16 + l15;
        b_[nt] = biasf[c]; cs_[nt] = csumf[c];
    }
    float ps[4][4], pq[4][4];
#pragma unroll
    for (int rt = 0; rt < 4; ++rt)
#pragma unroll
        for (int i = 0; i < 4; ++i){
            const int row = rt*16 + quad*4 + i;
            const float mr = sM[row], rr = sR[row];    // previous layer's (m*r, r)
            float s = 0.f, q = 0.f;
#pragma unroll
            for (int nt = 0; nt < 2; ++nt){
                float y = fmaxf(acc[nt][rt][i]*rr + (b_[nt] - mr*cs_[nt]), 0.f);
                acc[nt][rt][i] = y;
                s += y; q += y*y;
            }
            ps[rt][i] = s; pq[rt][i] = q;
        }
    // reduce across the 16 lanes of the quad group (shfl = LDS pipe, frees VALU)
#pragma unroll
    for (int off = 1; off <= 8; off <<= 1){
#pragma unroll
        for (int rt = 0; rt < 4; ++rt)
#pragma unroll
            for (int i = 0; i < 4; ++i){
                ps[rt][i] += __shfl_xor(ps[rt][i], off);
                pq[rt][i] += __shfl_xor(pq[rt][i], off);
            }
    }
    if (l15 == 0){
#pragma unroll
        for (int rt = 0; rt < 4; ++rt)
#pragma unroll
            for (int i = 0; i < 4; ++i){
                const int row = rt*16 + quad*4 + i;
                sRed[row*16 + wave*2 + 0] = ps[rt][i];
                sRed[row*16 + wave*2 + 1] = pq[rt][i];
            }
    }
    __syncthreads();                                    // drains all sIn reads too
    // write RAW y (bf16) — aliasing safe now; finalize next-layer stats in parallel
#pragma unroll
    for (int rt = 0; rt < 4; ++rt)
#pragma unroll
        for (int i = 0; i < 4; ++i){
            const int row = rt*16 + quad*4 + i;
#pragma unroll
            for (int nt = 0; nt < 2; ++nt)
                sOut[row*SH + colbase + nt*16 + l15] = f2b(acc[nt][rt][i]);
        }
    if (tid < 64){
        float ss = 0.f, qq = 0.f;
#pragma unroll
        for (int w = 0; w < 8; ++w){ ss += sRed[tid*16 + w*2]; qq += sRed[tid*16 + w*2 + 1]; }
        float m = ss * (1.f/256.f);
        float var = fmaxf(qq * (1.f/256.f) - m*m, 0.f);
        float r = rsqrtf(var + 1e-5f);
        sM[tid] = m * r; sR[tid] = r;
    }
    __syncthreads();
}

__global__ __launch_bounds__(512)
__attribute__((amdgpu_waves_per_eu(4, 8)))   // 128-VGPR budget (~96 live/wave) — NO SPILL
void bcq_main(
    const float* __restrict__ cum, const float* __restrict__ inp, const float* __restrict__ pos,
    const ushort_t* __restrict__ wbf, const float* __restrict__ wf, float* __restrict__ out)
{
    __shared__ __align__(16) char sMem[46592];
    ushort_t* sX     = (ushort_t*)sMem;            // 41984 B: raw x bf16 (stride SX, 64 rows)
    ushort_t* sH     = (ushort_t*)sMem;            // alias:   raw h     (stride SH, 33792 B)
    float*    sRed   = (float*)(sMem + 41984);     // 4096 B scratch (score buf aliases)
    float*    sScore = sRed;                       // 2560 B used at the end
    float*    sM     = (float*)(sMem + 46080);     // 256 B  (holds m*r per row)
    float*    sR     = (float*)(sMem + 46336);     // 256 B  (holds r per row)

    const int tid = threadIdx.x;
    const int r8 = tid >> 3, p8 = tid & 7;         // 8 threads per row, 64 rows
    const int tower = blockIdx.x & 1;              // pair adjacent blocks on one row-tile
    const size_t rowg = (size_t)(blockIdx.x >> 1) * BM;

    const float* cr = cum + (rowg + r8)*146;
    const float* ir = inp + (rowg + r8)*136;
    const float* pr = pos + (rowg + r8)*10;

    // ---- phase 0 (single pass): raw x -> LDS bf16, LN1 stats via shfl ----
    {
        float s = 0.f, sq = 0.f;
#pragma unroll
        for (int i = 0; i < 37; ++i){
            const int c = p8 + (i << 3);
            if (c < 292){
                float x = (c < 146) ? cr[c] : (c < 282) ? ir[c-146] : pr[c-282];
                s += x; sq += x*x;
                sX[r8*SX + c] = f2b(x);
            }
        }
        // zero sX cols [292,320) (A reads stop at 320)
#pragma unroll
        for (int j = 0; j < 4; ++j){
            const int c = 292 + p8 + (j << 3);
            if (c < 320) sX[r8*SX + c] = 0;
        }
#pragma unroll
        for (int off = 1; off <= 4; off <<= 1){ s += __shfl_xor(s, off); sq += __shfl_xor(sq, off); }
        if (p8 == 0){ sRed[r8*2] = s; sRed[r8*2 + 1] = sq; }
    }
    __syncthreads();
    if (tid < 64){
        float ss = sRed[tid*2], qq = sRed[tid*2 + 1];
        float m = ss * (1.f/292.f);
        float var = fmaxf(qq * (1.f/292.f) - m*m, 0.f);
        float r = rsqrtf(var + 1e-5f);
        sM[tid] = m * r; sR[tid] = r;
    }
    __syncthreads();

    if (tower == 0){
        // ================= value tower =================
        gemm64raw<10>(sX, SX, wbf + W1_OFF, wf + B1_OFF, wf + CS1_OFF, sH, sRed, sM, sR, tid);
        gemm64raw<8>(sH, SH, wbf + W2_OFF, wf + B2_OFF, wf + CS2_OFF, sH, sRed, sM, sR, tid);
        // value head on raw h2: r*dot(h2,w3') - (m*r)*cs3 + B3
        const ushort_t* ap = sH + r8*SH + p8*32;
        const float* w3 = wf + W3_OFF + p8*32;
        float s = 0.f;
#pragma unroll
        for (int c = 0; c < 32; ++c) s += b2f(ap[c]) * w3[c];
#pragma unroll
        for (int off = 1; off <= 4; off <<= 1) s += __shfl_xor(s, off);
        if (p8 == 0)
            out[rowg + r8] = s * sR[r8] - sM[r8] * wf[CS3_OFF] + wf[B3_OFF];
    } else {
        // ================= probability tower =================
        gemm64raw<10>(sX, SX, wbf + P1_OFF, wf + PB1_OFF, wf + CSP1_OFF, sH, sRed, sM, sR, tid);
        gemm64raw<8>(sH, SH, wbf + P2_OFF, wf + PB2_OFF, wf + CSP2_OFF, sH, sRed, sM, sR, tid);
        // score head (256->10) via MFMA on waves 0,1 (32 rows each), raw h2
        const int lane = tid & 63, wave = tid >> 6;
        const int l15 = lane & 15, quad = lane >> 4;
        if (wave < 2){
            const int rb = wave*32;
            const ushort_t* ar0 = sH + (rb + l15)*SH + quad*8;
            const ushort_t* ar1 = ar0 + 16*SH;
            const ushort_t* wl = wbf + P3BF_OFF + l15*32 + quad*8;
            floatx4 c0 = (floatx4){0,0,0,0}, c1 = (floatx4){0,0,0,0};
#pragma unroll
            for (int kc = 0; kc < 8; ++kc){
                short8 b  = *(const short8*)(wl + kc*512);
                short8 a0 = *(const short8*)(ar0 + kc*32);
                short8 a1 = *(const short8*)(ar1 + kc*32);
                c0 = __builtin_amdgcn_mfma_f32_16x16x32_bf16(a0, b, c0, 0, 0, 0);
                c1 = __builtin_amdgcn_mfma_f32_16x16x32_bf16(a1, b, c1, 0, 0, 0);
            }
            if (l15 < 10){
                const float bia = wf[PB3_OFF + l15];
                const float csp = wf[CSP3_OFF + l15];
#pragma unroll
                for (int i = 0; i < 4; ++i){
                    const int ra = rb + quad*4 + i, rbx = ra + 16;
                    sScore[ra*10  + l15] = c0[i]*sR[ra]  - sM[ra]*csp  + bia;
                    sScore[rbx*10 + l15] = c1[i]*sR[rbx] - sM[rbx]*csp + bia;
                }
            }
        }
        __syncthreads();
        if (tid < 64){
            float m = -1e30f;
#pragma unroll
            for (int j = 0; j < 10; ++j) m = fmaxf(m, sScore[tid*10 + j]);
            float l = 0.f;
#pragma unroll
            for (int j = 0; j < 10; ++j) l += expf(sScore[tid*10 + j] - m);
            l = logf(l);
            const size_t rg = rowg + tid;
#pragma unroll
            for (int j = 0; j < 10; ++j){
                const float sv = sScore[tid*10 + j];
                out[(size_t)NROWS    + rg*10 + j] = sv - m - l;
                out[(size_t)NROWS*11 + rg*10 + j] = sv;
            }
        }
    }
}

extern "C" void kernel_launch(void* const* d_in, const int* in_sizes, int n_in,
                              void* d_out, int out_size, void* d_ws, size_t ws_size,
                              hipStream_t stream) {
    (void)in_sizes; (void)n_in; (void)ws_size; (void)out_size;
    const float* cum  = (const float*)d_in[0];
    const float* inp  = (const float*)d_in[1];
    const float* pos  = (const float*)d_in[2];
    const float* ln1w = (const float*)d_in[3];
    const float* ln1b = (const float*)d_in[4];
    const float* ln2w = (const float*)d_in[5];
    const float* ln2b = (const float*)d_in[6];
    const float* ln3w = (const float*)d_in[7];
    const float* ln3b = (const float*)d_in[8];
    const float* n1g  = (const float*)d_in[9];
    const float* n1b  = (const float*)d_in[10];
    const float* n2g  = (const float*)d_in[11];
    const float* n2b  = (const float*)d_in[12];
    const float* n3g  = (const float*)d_in[13];
    const float* n3b  = (const float*)d_in[14];
    const float* p1w  = (const float*)d_in[15];
    const float* p1b  = (const float*)d_in[16];
    const float* p2w  = (const float*)d_in[17];
    const float* p2b  = (const float*)d_in[18];
    const float* p3w  = (const float*)d_in[19];
    const float* p3b  = (const float*)d_in[20];
    const float* pn1g = (const float*)d_in[21];
    const float* pn1b = (const float*)d_in[22];
    const float* pn2g = (const float*)d_in[23];
    const float* pn2b = (const float*)d_in[24];
    const float* pn3g = (const float*)d_in[25];
    const float* pn3b = (const float*)d_in[26];

    ushort_t* wbf = (ushort_t*)d_ws;
    float*    wf  = (float*)((char*)d_ws + BF16_BYTES);
    float*    out = (float*)d_out;

    hipLaunchKernelGGL(bcq_prep, dim3(645), dim3(256), 0, stream,
        ln1w, ln1b, ln2w, ln2b, ln3w, ln3b,
        n1g, n1b, n2g, n2b, n3g, n3b,
        p1w, p1b, p2w, p2b, p3w, p3b,
        pn1g, pn1b, pn2g, pn2b, pn3g, pn3b,
        wbf, wf);

    hipLaunchKernelGGL(bcq_main, dim3((NROWS/BM)*2), dim3(512), 0, stream,
        cum, inp, pos, wbf, wf, out);
}

// Round 10
// 390.396 us; speedup vs baseline: 1.1564x; 1.1529x over previous
//
#include <hip/hip_runtime.h>

typedef unsigned short ushort_t;
typedef unsigned int   uint_t;
typedef __attribute__((ext_vector_type(8))) short  short8;
typedef __attribute__((ext_vector_type(4))) float  floatx4;

#define NROWS 131072
#define BM    64      // rows per block (one tower per block)
#define SX    328     // x-hat bf16 LDS row stride (ushorts); cols >=292 zeroed to 320
#define SH    264     // h bf16 LDS row stride (ushorts)

// d_ws bf16 region (ushort element offsets) — chunk-major: [kc][col(256)][k(32)]
#define W1_OFF 0        // 10 chunks
#define P1_OFF 81920    // 10 chunks
#define W2_OFF 163840   // 8 chunks
#define P2_OFF 229376   // 8 chunks
#define P3BF_OFF 294912 // 8 chunks x [16 cols][32] bf16 frag layout (cols>=10 zero)
#define BF16_BYTES 598016
// d_ws float region (float element offsets, base = ws + BF16_BYTES)
#define B1_OFF  0
#define PB1_OFF 256
#define B2_OFF  512
#define PB2_OFF 768
#define W3_OFF  1024
#define B3_OFF  3840
#define PB3_OFF 3841

__device__ __forceinline__ float b2f(ushort_t u){
    union { uint_t i; float f; } v; v.i = ((uint_t)u) << 16; return v.f;
}
__device__ __forceinline__ ushort_t f2b(float f){
    union { uint_t i; float f; } v; v.f = f;
    uint_t b = v.i;
    b += 0x7FFFu + ((b >> 16) & 1u);   // RNE
    return (ushort_t)(b >> 16);
}

// ---------------- prologue: fold LN gain/bias into linears, fp32 -> bf16 ----
__global__ __launch_bounds__(256) void bcq_prep(
    const float* __restrict__ ln1w, const float* __restrict__ ln1b,
    const float* __restrict__ ln2w, const float* __restrict__ ln2b,
    const float* __restrict__ ln3w, const float* __restrict__ ln3b,
    const float* __restrict__ n1g,  const float* __restrict__ n1b,
    const float* __restrict__ n2g,  const float* __restrict__ n2b,
    const float* __restrict__ n3g,  const float* __restrict__ n3b,
    const float* __restrict__ p1w,  const float* __restrict__ p1b,
    const float* __restrict__ p2w,  const float* __restrict__ p2b,
    const float* __restrict__ p3w,  const float* __restrict__ p3b,
    const float* __restrict__ pn1g, const float* __restrict__ pn1b,
    const float* __restrict__ pn2g, const float* __restrict__ pn2b,
    const float* __restrict__ pn3g, const float* __restrict__ pn3b,
    ushort_t* __restrict__ wbf, float* __restrict__ wf)
{
    const int bid = blockIdx.x, tid = threadIdx.x;
    if (bid < 128){
        // layer 1 (K=292 padded to 320): W1 then P1
        for (int i = bid*256 + tid; i < 163840; i += 128*256){
            const int which = i / 81920;            // 0=W1, 1=P1
            const int r  = i - which*81920;
            const int kc = r >> 13;                  // /8192
            const int t  = r & 8191;
            const int c  = t >> 5, kk = t & 31;
            const int k  = kc*32 + kk;
            const float* src = which ? p1w  : ln1w;
            const float* g   = which ? pn1g : n1g;
            ushort_t v = 0;
            if (k < 292) v = f2b(src[c*292 + k] * g[k]);
            wbf[i] = v;
        }
        // layer 2 (K=256): W2 then P2
        for (int i = bid*256 + tid; i < 131072; i += 128*256){
            const int which = i >> 16;
            const int r  = i & 65535;
            const int kc = r >> 13;
            const int t  = r & 8191;
            const int c  = t >> 5, kk = t & 31;
            const int k  = kc*32 + kk;
            const float* src = which ? p2w  : ln2w;
            const float* g   = which ? pn2g : n2g;
            wbf[W2_OFF + i] = f2b(src[c*256 + k] * g[k]);
        }
    } else if (bid < 384){
        const int d = (bid - 128)*4 + (tid >> 6);
        const int lane = tid & 63;
        const float *w, *nb, *bs; int K, outoff; const int c = d & 255;
        if (d < 256)      { w = ln1w; nb = n1b;  bs = ln1b; K = 292; outoff = B1_OFF; }
        else if (d < 512) { w = p1w;  nb = pn1b; bs = p1b;  K = 292; outoff = PB1_OFF; }
        else if (d < 768) { w = ln2w; nb = n2b;  bs = ln2b; K = 256; outoff = B2_OFF; }
        else              { w = p2w;  nb = pn2b; bs = p2b;  K = 256; outoff = PB2_OFF; }
        float s = 0.f;
        for (int k = lane; k < K; k += 64) s += w[c*K + k] * nb[k];
        for (int off = 32; off; off >>= 1) s += __shfl_down(s, off);
        if (lane == 0) wf[outoff + c] = s + bs[c];
    } else if (bid == 384){
        wf[W3_OFF + tid] = ln3w[tid] * n3g[tid];
        // P3 in bf16 MFMA B-frag layout: [kc][col(16)][kk(32)], cols >=10 zero
        for (int i = tid; i < 4096; i += 256){
            const int kc = i >> 9, t = i & 511, c = t >> 5, kk = t & 31;
            const int k = kc*32 + kk;
            ushort_t vv = 0;
            if (c < 10) vv = f2b(p3w[c*256 + k] * pn3g[k]);
            wbf[P3BF_OFF + i] = vv;
        }
    } else {
        const int g32 = tid >> 5, l32 = tid & 31;
        const int d = (bid - 385)*8 + g32;                   // valid < 11
        if (d < 11){
            const float* w  = (d == 0) ? ln3w : (p3w + (d-1)*256);
            const float* nb = (d == 0) ? n3b  : pn3b;
            float s = 0.f;
            for (int k = l32; k < 256; k += 32) s += w[k] * nb[k];
            for (int off = 16; off; off >>= 1) s += __shfl_xor(s, off);
            if (l32 == 0){
                if (d == 0) wf[B3_OFF] = s + ln3b[0];
                else        wf[PB3_OFF + d - 1] = s + p3b[d - 1];
            }
        }
    }
}

// ---------------- main ------------------------------------------------------
// GEMM: y[64x256] = relu(sIn @ W'^T + b'); fused LN epilogue writes normalized
// bf16 to sOut. 8 waves: wave w owns cols [w*32, w*32+32) over ALL 64 rows.
// Per kc: 4 A-frags (LDS), 2 B-frags (L2), 8 MFMAs. DEPTH-4 B prefetch ring:
// ~480cyc lookahead ≈ loaded-L2 latency (depth-2's 240cyc left ~1 kc exposed).
// Peak live ≈ 110 unified (bb 32 + bnew 8 + a 16 + acc 32 AGPR + addr) ≤ 128.
// Safe for sOut aliasing sIn: all sIn reads complete before internal barrier 1.
template<int FULLKC>
__device__ __forceinline__ void gemm64ln(
    const ushort_t* sIn, int astride, const ushort_t* __restrict__ Wg,
    const float* __restrict__ biasf, ushort_t* sOut,
    float* sRed, float* sM, float* sR, int tid)
{
    const int lane = tid & 63, wave = tid >> 6;        // 8 waves
    const int l15 = lane & 15, quad = lane >> 4;
    const int colbase = wave * 32;
    const ushort_t* arow = sIn + l15*astride + quad*8; // + rt*16*astride + kc*32
    // chunk-major: frag addr = (colbase + nt*16 + l15)*32 + quad*8 + kc*8192
    const ushort_t* wl = Wg + (colbase + l15)*32 + quad*8;

    floatx4 acc[2][4];                                 // [nt][rt] = 32 AGPRs
#pragma unroll
    for (int nt = 0; nt < 2; ++nt)
#pragma unroll
        for (int rt = 0; rt < 4; ++rt) acc[nt][rt] = (floatx4){0,0,0,0};

    short8 bb[4][2];                                   // depth-4 prefetch ring (32 VGPR)
#pragma unroll
    for (int s4 = 0; s4 < 4; ++s4)
#pragma unroll
        for (int nt = 0; nt < 2; ++nt)
            bb[s4][nt] = *(const short8*)(wl + nt*512 + s4*8192);

#pragma unroll
    for (int kc = 0; kc < FULLKC; ++kc){
        short8 bnew[2];
        if (kc + 4 < FULLKC){
#pragma unroll
            for (int nt = 0; nt < 2; ++nt)
                bnew[nt] = *(const short8*)(wl + nt*512 + (kc + 4)*8192);
        }
        short8 a[4];
#pragma unroll
        for (int rt = 0; rt < 4; ++rt)
            a[rt] = *(const short8*)(arow + rt*16*astride + kc*32);
#pragma unroll
        for (int nt = 0; nt < 2; ++nt){
            const short8 bc = bb[kc & 3][nt];          // kc&3 is compile-time (full unroll)
#pragma unroll
            for (int rt = 0; rt < 4; ++rt)
                acc[nt][rt] = __builtin_amdgcn_mfma_f32_16x16x32_bf16(a[rt], bc, acc[nt][rt], 0, 0, 0);
        }
        if (kc + 4 < FULLKC){
#pragma unroll
            for (int nt = 0; nt < 2; ++nt) bb[kc & 3][nt] = bnew[nt];
        }
    }

    // ---- fused LN epilogue ----
    float bia[2];
#pragma unroll
    for (int nt = 0; nt < 2; ++nt) bia[nt] = biasf[colbase + nt*16 + l15];

    // y = relu(acc+bias) stored back into acc; per-(rt,i) row partials over 2 col-tiles
    float ps[4][4], pq[4][4];
#pragma unroll
    for (int rt = 0; rt < 4; ++rt)
#pragma unroll
        for (int i = 0; i < 4; ++i){
            float s = 0.f, q = 0.f;
#pragma unroll
            for (int nt = 0; nt < 2; ++nt){
                float y = fmaxf(acc[nt][rt][i] + bia[nt], 0.f);
                acc[nt][rt][i] = y;
                s += y; q += y*y;
            }
            ps[rt][i] = s; pq[rt][i] = q;
        }
    // reduce across the 16 lanes (cols) of the quad group
#pragma unroll
    for (int off = 1; off <= 8; off <<= 1){
#pragma unroll
        for (int rt = 0; rt < 4; ++rt)
#pragma unroll
            for (int i = 0; i < 4; ++i){
                ps[rt][i] += __shfl_xor(ps[rt][i], off);
                pq[rt][i] += __shfl_xor(pq[rt][i], off);
            }
    }
    if (l15 == 0){
#pragma unroll
        for (int rt = 0; rt < 4; ++rt)
#pragma unroll
            for (int i = 0; i < 4; ++i){
                const int row = rt*16 + quad*4 + i;
                sRed[row*16 + wave*2 + 0] = ps[rt][i];
                sRed[row*16 + wave*2 + 1] = pq[rt][i];
            }
    }
    __syncthreads();                                   // also drains all sIn reads
    if (tid < 64){
        float ss = 0.f, qq = 0.f;
#pragma unroll
        for (int w = 0; w < 8; ++w){ ss += sRed[tid*16 + w*2]; qq += sRed[tid*16 + w*2 + 1]; }
        float m = ss * (1.f/256.f);
        float var = fmaxf(qq * (1.f/256.f) - m*m, 0.f);
        sM[tid] = m; sR[tid] = rsqrtf(var + 1e-5f);
    }
    __syncthreads();
    // normalize from registers, write bf16 (sOut may alias sIn — reads done)
#pragma unroll
    for (int rt = 0; rt < 4; ++rt)
#pragma unroll
        for (int i = 0; i < 4; ++i){
            const int row = rt*16 + quad*4 + i;
            const float m = sM[row], r = sR[row];
#pragma unroll
            for (int nt = 0; nt < 2; ++nt)
                sOut[row*SH + colbase + nt*16 + l15] = f2b((acc[nt][rt][i] - m) * r);
        }
}

__global__ __launch_bounds__(512)
__attribute__((amdgpu_waves_per_eu(4, 8)))   // 128-VGPR budget (~110 live/wave) — NO SPILL
void bcq_main(
    const float* __restrict__ cum, const float* __restrict__ inp, const float* __restrict__ pos,
    const ushort_t* __restrict__ wbf, const float* __restrict__ wf, float* __restrict__ out)
{
    // 46592 B LDS; registers cap residency at 2 blocks/CU (16 waves)
    __shared__ __align__(16) char sMem[46592];
    ushort_t* sX     = (ushort_t*)sMem;            // 41984 B: x-hat (stride SX, 64 rows)
    ushort_t* sH     = (ushort_t*)sMem;            // alias:   h     (stride SH, 33792 B)
    float*    sRed   = (float*)(sMem + 41984);     // 4096 B scratch (score buf aliases)
    float*    sScore = sRed;                       // 2560 B used at the end
    float*    sM     = (float*)(sMem + 46080);     // 256 B
    float*    sR     = (float*)(sMem + 46336);     // 256 B

    const int tid = threadIdx.x;
    const int r8 = tid >> 3, p8 = tid & 7;         // 8 threads per row, 64 rows
    const int tower = blockIdx.x & 1;              // pair adjacent blocks on one row-tile
    const size_t rowg = (size_t)(blockIdx.x >> 1) * BM;

    const float* cr = cum + (rowg + r8)*146;
    const float* ir = inp + (rowg + r8)*136;
    const float* pr = pos + (rowg + r8)*10;

    // ---- phase 0, pass 1: LN1 stats ONLY — x not kept live across barriers
    {
        float s = 0.f, sq = 0.f;
#pragma unroll
        for (int i = 0; i < 37; ++i){
            const int c = p8 + (i << 3);
            if (c < 292){
                float x = (c < 146) ? cr[c] : (c < 282) ? ir[c-146] : pr[c-282];
                s += x; sq += x*x;
            }
        }
#pragma unroll
        for (int off = 1; off <= 4; off <<= 1){ s += __shfl_xor(s, off); sq += __shfl_xor(sq, off); }
        if (p8 == 0){ sRed[r8*2] = s; sRed[r8*2 + 1] = sq; }
        // zero sX cols [292,320) (A reads stop at 320)
#pragma unroll
        for (int j = 0; j < 4; ++j){
            const int c = 292 + p8 + (j << 3);
            if (c < 320) sX[r8*SX + c] = 0;
        }
    }
    __syncthreads();
    if (tid < 64){
        float ss = sRed[tid*2], qq = sRed[tid*2 + 1];
        float m = ss * (1.f/292.f);
        float var = fmaxf(qq * (1.f/292.f) - m*m, 0.f);
        sM[tid] = m; sR[tid] = rsqrtf(var + 1e-5f);
    }
    __syncthreads();
    asm volatile("" ::: "memory");   // force x re-load (L2-hot) — no big live range
    // ---- phase 0, pass 2: reload x, normalize, store bf16 x-hat ----
    {
        const float mr = sM[r8], rs = sR[r8];
#pragma unroll
        for (int i = 0; i < 37; ++i){
            const int c = p8 + (i << 3);
            if (c < 292){
                float x = (c < 146) ? cr[c] : (c < 282) ? ir[c-146] : pr[c-282];
                sX[r8*SX + c] = f2b((x - mr) * rs);
            }
        }
    }
    __syncthreads();

    if (tower == 0){
        // ================= value tower =================
        gemm64ln<10>(sX, SX, wbf + W1_OFF, wf + B1_OFF, sH, sRed, sM, sR, tid);
        __syncthreads();
        gemm64ln<8>(sH, SH, wbf + W2_OFF, wf + B2_OFF, sH, sRed, sM, sR, tid);
        __syncthreads();
        // value head: dot(x-hat3, w3') + B3, 8 threads/row over 64 rows
        const ushort_t* ap = sH + r8*SH + p8*32;
        const float* w3 = wf + W3_OFF + p8*32;
        float s = 0.f;
#pragma unroll
        for (int c = 0; c < 32; ++c) s += b2f(ap[c]) * w3[c];
#pragma unroll
        for (int off = 1; off <= 4; off <<= 1) s += __shfl_xor(s, off);
        if (p8 == 0) sRed[r8] = s;
        __syncthreads();
        if (tid < 64) out[rowg + tid] = sRed[tid] + wf[B3_OFF];
    } else {
        // ================= probability tower =================
        gemm64ln<10>(sX, SX, wbf + P1_OFF, wf + PB1_OFF, sH, sRed, sM, sR, tid);
        __syncthreads();
        gemm64ln<8>(sH, SH, wbf + P2_OFF, wf + PB2_OFF, sH, sRed, sM, sR, tid);
        __syncthreads();
        // score head (256->10) via MFMA on waves 0,1 (32 rows each)
        const int lane = tid & 63, wave = tid >> 6;
        const int l15 = lane & 15, quad = lane >> 4;
        if (wave < 2){
            const int rb = wave*32;
            const ushort_t* ar0 = sH + (rb + l15)*SH + quad*8;
            const ushort_t* ar1 = ar0 + 16*SH;
            const ushort_t* wl = wbf + P3BF_OFF + l15*32 + quad*8;
            floatx4 c0 = (floatx4){0,0,0,0}, c1 = (floatx4){0,0,0,0};
#pragma unroll
            for (int kc = 0; kc < 8; ++kc){
                short8 b  = *(const short8*)(wl + kc*512);
                short8 a0 = *(const short8*)(ar0 + kc*32);
                short8 a1 = *(const short8*)(ar1 + kc*32);
                c0 = __builtin_amdgcn_mfma_f32_16x16x32_bf16(a0, b, c0, 0, 0, 0);
                c1 = __builtin_amdgcn_mfma_f32_16x16x32_bf16(a1, b, c1, 0, 0, 0);
            }
            if (l15 < 10){
                const float bia = wf[PB3_OFF + l15];
#pragma unroll
                for (int i = 0; i < 4; ++i){
                    sScore[(rb + quad*4 + i)*10 + l15]      = c0[i] + bia;
                    sScore[(rb + 16 + quad*4 + i)*10 + l15] = c1[i] + bia;
                }
            }
        }
        __syncthreads();
        if (tid < 64){
            float m = -1e30f;
#pragma unroll
            for (int j = 0; j < 10; ++j) m = fmaxf(m, sScore[tid*10 + j]);
            float l = 0.f;
#pragma unroll
            for (int j = 0; j < 10; ++j) l += expf(sScore[tid*10 + j] - m);
            l = logf(l);
            const size_t rg = rowg + tid;
#pragma unroll
            for (int j = 0; j < 10; ++j){
                const float sv = sScore[tid*10 + j];
                out[(size_t)NROWS    + rg*10 + j] = sv - m - l;
                out[(size_t)NROWS*11 + rg*10 + j] = sv;
            }
        }
    }
}

extern "C" void kernel_launch(void* const* d_in, const int* in_sizes, int n_in,
                              void* d_out, int out_size, void* d_ws, size_t ws_size,
                              hipStream_t stream) {
    (void)in_sizes; (void)n_in; (void)ws_size; (void)out_size;
    const float* cum  = (const float*)d_in[0];
    const float* inp  = (const float*)d_in[1];
    const float* pos  = (const float*)d_in[2];
    const float* ln1w = (const float*)d_in[3];
    const float* ln1b = (const float*)d_in[4];
    const float* ln2w = (const float*)d_in[5];
    const float* ln2b = (const float*)d_in[6];
    const float* ln3w = (const float*)d_in[7];
    const float* ln3b = (const float*)d_in[8];
    const float* n1g  = (const float*)d_in[9];
    const float* n1b  = (const float*)d_in[10];
    const float* n2g  = (const float*)d_in[11];
    const float* n2b  = (const float*)d_in[12];
    const float* n3g  = (const float*)d_in[13];
    const float* n3b  = (const float*)d_in[14];
    const float* p1w  = (const float*)d_in[15];
    const float* p1b  = (const float*)d_in[16];
    const float* p2w  = (const float*)d_in[17];
    const float* p2b  = (const float*)d_in[18];
    const float* p3w  = (const float*)d_in[19];
    const float* p3b  = (const float*)d_in[20];
    const float* pn1g = (const float*)d_in[21];
    const float* pn1b = (const float*)d_in[22];
    const float* pn2g = (const float*)d_in[23];
    const float* pn2b = (const float*)d_in[24];
    const float* pn3g = (const float*)d_in[25];
    const float* pn3b = (const float*)d_in[26];

    ushort_t* wbf = (ushort_t*)d_ws;
    float*    wf  = (float*)((char*)d_ws + BF16_BYTES);
    float*    out = (float*)d_out;

    hipLaunchKernelGGL(bcq_prep, dim3(387), dim3(256), 0, stream,
        ln1w, ln1b, ln2w, ln2b, ln3w, ln3b,
        n1g, n1b, n2g, n2b, n3g, n3b,
        p1w, p1b, p2w, p2b, p3w, p3b,
        pn1g, pn1b, pn2g, pn2b, pn3g, pn3b,
        wbf, wf);

    hipLaunchKernelGGL(bcq_main, dim3((NROWS/BM)*2), dim3(512), 0, stream,
        cum, inp, pos, wbf, wf, out);
}